// Round 14
// baseline (348.640 us; speedup 1.0000x reference)
//
#include <hip/hip_runtime.h>

#define BB 2
#define LL 4096
#define SS 4096
#define HH 8
#define DD 64
#define UU 45
#define SCALE 0.125f
#define NCH 32     // softmax/context chunks of 128 s
#define CHK 128
#define GCH 256    // gather: l per chunk (16 chunks)
#define GTS 64     // gather: s per tile (64 tiles)

// ---------------------------------------------------------------------------
// Index build (once; idx shared across b,h). Bucket = (l>>8)*64 + (s>>6).
// Entry = (s<<14) | (l&255)<<6 | u  (26 bits).
// ---------------------------------------------------------------------------
__global__ __launch_bounds__(256) void k_hist(
    const int* __restrict__ idx, int* __restrict__ hist) {
  int e = blockIdx.x * 256 + threadIdx.x;       // 184320 exact
  int l = e / UU;
  int s = idx[e];
  atomicAdd(&hist[(l >> 8) * 64 + (s >> 6)], 1);
}

__global__ __launch_bounds__(256) void k_scan(
    const int* __restrict__ hist, int* __restrict__ off) {
  __shared__ int tmp[256];
  int tid = threadIdx.x;
  int v0 = hist[tid*4], v1 = hist[tid*4+1], v2 = hist[tid*4+2], v3 = hist[tid*4+3];
  int ts = v0 + v1 + v2 + v3;
  tmp[tid] = ts;
  __syncthreads();
  for (int st = 1; st < 256; st <<= 1) {
    int add = (tid >= st) ? tmp[tid - st] : 0;
    __syncthreads();
    tmp[tid] += add;
    __syncthreads();
  }
  int run = tmp[tid] - ts;                      // exclusive prefix
  off[tid*4] = run; run += v0;
  off[tid*4+1] = run; run += v1;
  off[tid*4+2] = run; run += v2;
  off[tid*4+3] = run; run += v3;
  if (tid == 255) off[1024] = run;
}

__global__ __launch_bounds__(256) void k_scatter(
    const int* __restrict__ idx, const int* __restrict__ off,
    int* __restrict__ cursor, unsigned* __restrict__ entries) {
  int e = blockIdx.x * 256 + threadIdx.x;
  int l = e / UU, u = e - l * UU;
  int s = idx[e];
  int bkt = (l >> 8) * 64 + (s >> 6);
  int pos = atomicAdd(&cursor[bkt], 1);
  entries[off[bkt] + pos] =
      ((unsigned)s << 14) | ((unsigned)(l & 255) << 6) | (unsigned)u;
}

// ---------------------------------------------------------------------------
// K1-new: sorted-stream gather. Block = (l-chunk of 256, bh); 256 blocks
// (1/CU, bh in low 4 bits -> XCD pin). Q chunk + dots in LDS; K streamed
// in 64-row tiles (reg-staged, T14 issue-early/store-late). Entries
// processed by 16-lane groups from LDS. Final reduce in u-order with the
// SAME dot+shuffle sequence as the old kernel -> bit-identical M.
// ---------------------------------------------------------------------------
__device__ __forceinline__ void proc_entry(
    unsigned ent, const float* Qt, const float* Kt, float* dots, int sub) {
  int sl = (ent >> 14) & 63;
  int ll = (ent >> 6) & 255;
  int uu = ent & 63;
  float4 kk = ((const float4*)Kt)[sl * 16 + sub];
  float4 qv = ((const float4*)Qt)[ll * 16 + sub];
  float p = qv.x * kk.x + qv.y * kk.y + qv.z * kk.z + qv.w * kk.w;
  p += __shfl_xor(p, 8, 16);
  p += __shfl_xor(p, 4, 16);
  p += __shfl_xor(p, 2, 16);
  p += __shfl_xor(p, 1, 16);
  if (sub == 0) dots[ll * UU + uu] = p;
}

__global__ __launch_bounds__(256, 1) void k_gather_M(
    const float* __restrict__ q, const float* __restrict__ k,
    const unsigned* __restrict__ entries, const int* __restrict__ off,
    float* __restrict__ M) {
  __shared__ float Qt[GCH * DD];        // 64 KB
  __shared__ float dots[GCH * UU];      // 45 KB
  __shared__ float Kt[GTS * DD];        // 16 KB
  int tid = threadIdx.x;
  int bh = blockIdx.x & 15;             // XCD pin
  int chunk = blockIdx.x >> 4;          // 16 chunks
  int b = bh >> 3, h = bh & 7;
  int l0 = chunk * GCH;
  int g = tid >> 4, sub = tid & 15;

  const float4* qb4 = (const float4*)q;
  for (int i4 = tid; i4 < GCH * 16; i4 += 256)
    ((float4*)Qt)[i4] = qb4[(((long)b * LL + l0 + (i4 >> 4)) * HH + h) * 16 + (i4 & 15)];

  const float4* kb4 = (const float4*)(k + ((long)b * SS * HH + h) * DD);
  // prologue: stage tile 0
  #pragma unroll
  for (int j = 0; j < 4; ++j) {
    int fi = j * 256 + tid;
    ((float4*)Kt)[fi] = kb4[(long)(fi >> 4) * 128 + (fi & 15)];
  }
  __syncthreads();

  for (int t = 0; t < 64; ++t) {
    float4 s0, s1, s2, s3;
    if (t < 63) {                       // issue next-tile loads early
      int base = (t + 1) * GTS;
      int f0 = tid, f1 = 256 + tid, f2 = 512 + tid, f3 = 768 + tid;
      s0 = kb4[(long)(base + (f0 >> 4)) * 128 + (f0 & 15)];
      s1 = kb4[(long)(base + (f1 >> 4)) * 128 + (f1 & 15)];
      s2 = kb4[(long)(base + (f2 >> 4)) * 128 + (f2 & 15)];
      s3 = kb4[(long)(base + (f3 >> 4)) * 128 + (f3 & 15)];
    }
    // process tile t
    int eb = off[(chunk << 6) + t];
    int ee = off[(chunk << 6) + t + 1];
    int e = eb + g;
    for (; e + 48 < ee; e += 64) {      // 4 independent entries per step
      unsigned n0 = entries[e], n1 = entries[e + 16];
      unsigned n2 = entries[e + 32], n3 = entries[e + 48];
      proc_entry(n0, Qt, Kt, dots, sub);
      proc_entry(n1, Qt, Kt, dots, sub);
      proc_entry(n2, Qt, Kt, dots, sub);
      proc_entry(n3, Qt, Kt, dots, sub);
    }
    for (; e < ee; e += 16) proc_entry(entries[e], Qt, Kt, dots, sub);
    __syncthreads();                    // Kt reads done
    if (t < 63) {
      ((float4*)Kt)[tid] = s0;
      ((float4*)Kt)[256 + tid] = s1;
      ((float4*)Kt)[512 + tid] = s2;
      ((float4*)Kt)[768 + tid] = s3;
    }
    __syncthreads();                    // stores visible
  }

  // final reduce, u-order (bit-identical to old kernel)
  float mx = -INFINITY, sm = 0.f;
  #pragma unroll
  for (int u = 0; u < UU; ++u) {
    float p = dots[tid * UU + u];
    mx = fmaxf(mx, p);
    sm += p;
  }
  M[(long)bh * LL + l0 + tid] = mx - sm * (1.0f / SS);
}

// ---------------------------------------------------------------------------
// K1 fallback (proven 48.5us version) when ws too small.
// ---------------------------------------------------------------------------
__global__ __launch_bounds__(256) void k_compute_M(
    const float* __restrict__ q, const float* __restrict__ k,
    const int* __restrict__ idx, float* __restrict__ M) {
  __shared__ int sidx[16 * UU];
  int tid = threadIdx.x;
  int bh = blockIdx.x & 15;
  int l0 = (blockIdx.x >> 4) << 4;
  for (int i = tid; i < 16 * UU; i += 256) sidx[i] = idx[(long)l0 * UU + i];
  __syncthreads();
  int slot = tid >> 4, sub = tid & 15;
  int l = l0 + slot;
  int b = bh >> 3, h = bh & 7;
  const float4* qp = (const float4*)(q + (((long)b * LL + l) * HH + h) * DD);
  float4 qq = qp[sub];
  const float* kb = k + (long)b * SS * HH * DD + h * DD;
  float mx = -INFINITY, sm = 0.f;
  #pragma unroll 5
  for (int u = 0; u < UU; ++u) {
    int s = sidx[slot * UU + u];
    float4 kk4 = ((const float4*)(kb + (long)s * (HH * DD)))[sub];
    float p = qq.x * kk4.x + qq.y * kk4.y + qq.z * kk4.z + qq.w * kk4.w;
    #pragma unroll
    for (int off = 8; off; off >>= 1) p += __shfl_xor(p, off, 16);
    mx = fmaxf(mx, p);
    sm += p;
  }
  if (sub == 0) M[(long)bh * LL + l] = mx - sm * (1.0f / SS);
}

// ---------------------------------------------------------------------------
// K2: top-45 per (b,h) via 4-pass radix-select; jax.lax.top_k semantics.
// ---------------------------------------------------------------------------
__global__ __launch_bounds__(256) void k_topk(
    const float* __restrict__ M, int* __restrict__ Mtop) {
  __shared__ unsigned keys[LL];
  __shared__ int hist[256];
  __shared__ int wsum[4];
  __shared__ int sh_bin, sh_gtwin;
  __shared__ int ccount, ecount;
  __shared__ unsigned cand_key[64];
  __shared__ int cand_idx[64];
  __shared__ int elist[LL];

  int bh = blockIdx.x, tid = threadIdx.x;
  int lane = tid & 63, w = tid >> 6;
  const float* m = M + (long)bh * LL;
  for (int i = tid; i < LL; i += 256) {
    union { float f; unsigned u; } cv; cv.f = m[i];
    keys[i] = (cv.u & 0x80000000u) ? ~cv.u : (cv.u | 0x80000000u);
  }
  if (tid == 0) { ccount = 0; ecount = 0; }
  __syncthreads();

  unsigned prefix = 0, pmask = 0;
  int need = UU, above = 0;

  for (int shift = 24; shift >= 0; shift -= 8) {
    hist[tid] = 0;
    __syncthreads();
    #pragma unroll
    for (int j = 0; j < 16; ++j) {
      unsigned kk = keys[tid + (j << 8)];
      if ((kk & pmask) == prefix) atomicAdd(&hist[(kk >> shift) & 255], 1);
    }
    __syncthreads();
    int v = hist[tid];
    int sfx = v;
    #pragma unroll
    for (int st = 1; st < 64; st <<= 1) {
      int o = __shfl_down(sfx, st, 64);
      if (lane + st < 64) sfx += o;
    }
    if (lane == 0) wsum[w] = sfx;
    __syncthreads();
    for (int t = w + 1; t < 4; ++t) sfx += wsum[t];
    int gt = sfx - v;
    if (gt < need && sfx >= need) {
      sh_bin = tid;
      sh_gtwin = gt;
    }
    __syncthreads();
    prefix |= ((unsigned)sh_bin << shift);
    pmask  |= (255u << shift);
    need  -= sh_gtwin;
    above += sh_gtwin;
    __syncthreads();
  }
  unsigned T = prefix;

  #pragma unroll
  for (int j = 0; j < 16; ++j) {
    int i = tid + (j << 8);
    unsigned kk = keys[i];
    if (kk > T)      { int p = atomicAdd(&ccount, 1); cand_key[p] = kk; cand_idx[p] = i; }
    else if (kk == T){ int p = atomicAdd(&ecount, 1); elist[p] = i; }
  }
  __syncthreads();
  int nc = ccount, ne = ecount;
  for (int t = tid; t < nc; t += 256) {
    unsigned kk = cand_key[t]; int ii = cand_idx[t]; int r = 0;
    for (int j = 0; j < nc; ++j)
      r += (cand_key[j] > kk) || (cand_key[j] == kk && cand_idx[j] < ii);
    Mtop[bh * UU + r] = ii;
  }
  for (int t = tid; t < ne; t += 256) {
    int ii = elist[t]; int r = 0;
    for (int j = 0; j < ne; ++j) r += (elist[j] < ii);
    if (r < need) Mtop[bh * UU + above + r] = ii;
  }
}

// ---------------------------------------------------------------------------
// KF: fused scores + exp + chunk-sum + context-partial (r13 version).
// ---------------------------------------------------------------------------
__global__ __launch_bounds__(256) void k_fused(
    const float* __restrict__ q, const float* __restrict__ k,
    const float* __restrict__ v, const int* __restrict__ Mtop,
    float* __restrict__ attn, float* __restrict__ part,
    float* __restrict__ stats) {
  __shared__ float smem[4 * UU * DD];
  __shared__ float gl[UU];
  float* qr = smem;
  float* sp = smem + UU * DD;

  int ch = blockIdx.x, bh = blockIdx.y;
  int b = bh >> 3, h = bh & 7;
  int tid = threadIdx.x;
  int lane = tid & 63, w = tid >> 6;
  int s0 = ch * CHK;

  for (int i = tid; i < UU * DD; i += 256) {
    int u = i >> 6, d = i & 63;
    int l = Mtop[bh * UU + u];
    qr[i] = q[(((long)b * LL + l) * HH + h) * DD + d];
  }
  __syncthreads();

  {
    int slb = tid & 63;
    int uq  = tid >> 6;
    const float4* kp0 = (const float4*)(k + (((long)b * SS + s0 + slb) * HH + h) * DD);
    const float4* kp1 = (const float4*)(k + (((long)b * SS + s0 + slb + 64) * HH + h) * DD);
    float4 kr0[16], kr1[16];
    #pragma unroll
    for (int j = 0; j < 16; ++j) { kr0[j] = kp0[j]; kr1[j] = kp1[j]; }
    int ub = (uq == 0) ? 0 : 12 + (uq - 1) * 11;
    int ue = ub + ((uq == 0) ? 12 : 11);
    for (int u = ub; u < ue; ++u) {
      const float4* qp = (const float4*)(qr + u * DD);
      float a0 = 0.f, a1 = 0.f, c0 = 0.f, c1 = 0.f;
      #pragma unroll
      for (int j = 0; j < 8; ++j) {
        float4 qA = qp[j], qB = qp[j + 8];
        float4 kA0 = kr0[j], kB0 = kr0[j + 8];
        float4 kA1 = kr1[j], kB1 = kr1[j + 8];
        a0 += qA.x * kA0.x + qA.y * kA0.y + qA.z * kA0.z + qA.w * kA0.w;
        a1 += qB.x * kB0.x + qB.y * kB0.y + qB.z * kB0.z + qB.w * kB0.w;
        c0 += qA.x * kA1.x + qA.y * kA1.y + qA.z * kA1.z + qA.w * kA1.w;
        c1 += qB.x * kB1.x + qB.y * kB1.y + qB.z * kB1.z + qB.w * kB1.w;
      }
      sp[slb * 52 + u]        = __expf((a0 + a1) * SCALE);
      sp[(slb + 64) * 52 + u] = __expf((c0 + c1) * SCALE);
    }
  }
  __syncthreads();

  for (int i = tid; i < UU * CHK; i += 256) {
    int u = i >> 7, sl = i & 127;
    attn[((long)bh * UU + u) * SS + s0 + sl] = sp[sl * 52 + u];
  }
  for (int u = w; u < UU; u += 4) {
    float e = sp[lane * 52 + u] + sp[(lane + 64) * 52 + u];
    #pragma unroll
    for (int off = 32; off; off >>= 1) e += __shfl_xor(e, off, 64);
    if (lane == 0) gl[u] = e;
  }
  float acc[UU];
  #pragma unroll
  for (int u = 0; u < UU; ++u) acc[u] = 0.f;
  const float* vb = v + (long)b * SS * HH * DD + h * DD + lane;
  #pragma unroll 2
  for (int j = 0; j < 32; ++j) {
    int sl = (j << 2) + w;
    float vd = vb[(long)(s0 + sl) * (HH * DD)];
    const float* ar = sp + sl * 52;
    #pragma unroll
    for (int g2 = 0; g2 < 11; ++g2) {
      float4 aa = *(const float4*)(ar + g2 * 4);
      acc[g2 * 4 + 0] += aa.x * vd;
      acc[g2 * 4 + 1] += aa.y * vd;
      acc[g2 * 4 + 2] += aa.z * vd;
      acc[g2 * 4 + 3] += aa.w * vd;
    }
    acc[44] += ar[44] * vd;
  }

  __syncthreads();
  #pragma unroll
  for (int u = 0; u < UU; ++u) smem[(w * UU + u) * DD + lane] = acc[u];
  __syncthreads();
  long base = ((long)bh * NCH + ch) * (UU * DD);
  for (int i = tid; i < UU * DD; i += 256)
    part[base + i] = smem[i] + smem[UU * DD + i] + smem[2 * UU * DD + i] + smem[3 * UU * DD + i];
  if (tid < UU)
    stats[((long)bh * UU + tid) * NCH + ch] = gl[tid];
}

// ---------------------------------------------------------------------------
// KE: epilogue (r12/r13 version).
// ---------------------------------------------------------------------------
__global__ __launch_bounds__(256) void k_epilogue(
    const float* __restrict__ stats, const float* __restrict__ part,
    float* __restrict__ attn, float* __restrict__ ctx) {
  __shared__ float sinv;
  int bid = blockIdx.x, tid = threadIdx.x;
  if (bid < BB * HH * UU) {
    long row = bid;
    const float* st = stats + row * NCH;
    if (tid == 0) {
      float L = 0.f;
      #pragma unroll
      for (int c = 0; c < NCH; ++c) L += st[c];
      sinv = 1.0f / L;
    }
    __syncthreads();
    float inv = sinv;
    float4* a = (float4*)(attn + row * SS);
    #pragma unroll
    for (int g = 0; g < 4; ++g) {
      int i4 = g * 256 + tid;
      float4 vv = a[i4];
      vv.x *= inv; vv.y *= inv; vv.z *= inv; vv.w *= inv;
      a[i4] = vv;
    }
  } else {
    int e = (bid - BB * HH * UU) * 256 + tid;
    int bh = e / (UU * DD);
    int r = e - bh * (UU * DD);
    int u = r >> 6;
    const float* st = stats + ((long)bh * UU + u) * NCH;
    float L = 0.f, s = 0.f;
    #pragma unroll
    for (int c = 0; c < NCH; ++c) {
      L += st[c];
      s += part[((long)bh * NCH + c) * (UU * DD) + r];
    }
    ctx[e] = s / L;
  }
}

// --------------------- fallback path (small ws) ----------------------------
__global__ __launch_bounds__(256) void k_scores(
    const float* __restrict__ q, const float* __restrict__ k,
    const int* __restrict__ Mtop, float* __restrict__ attn) {
  __shared__ float qr[UU * DD];
  int bh = blockIdx.y;
  int b = bh >> 3, h = bh & 7;
  for (int i = threadIdx.x; i < UU * DD; i += 256) {
    int u = i >> 6, d = i & 63;
    int l = Mtop[bh * UU + u];
    qr[i] = q[(((long)b * LL + l) * HH + h) * DD + d];
  }
  __syncthreads();
  int s = blockIdx.x * 256 + threadIdx.x;
  float4 kr[16];
  const float4* kp = (const float4*)(k + (((long)b * SS + s) * HH + h) * DD);
  #pragma unroll
  for (int j = 0; j < 16; ++j) kr[j] = kp[j];
  for (int u = 0; u < UU; ++u) {
    const float4* qp = (const float4*)(qr + u * DD);
    float acc = 0.f;
    #pragma unroll
    for (int j = 0; j < 16; ++j) {
      float4 qq = qp[j];
      acc += qq.x * kr[j].x + qq.y * kr[j].y + qq.z * kr[j].z + qq.w * kr[j].w;
    }
    attn[((long)bh * UU + u) * SS + s] = acc * SCALE;
  }
}

__global__ __launch_bounds__(256) void k_softmax(float* __restrict__ attn) {
  __shared__ float red[256];
  long row = blockIdx.x;
  float* a = attn + row * SS;
  float v[16];
  float mx = -INFINITY;
  #pragma unroll
  for (int j = 0; j < 16; ++j) {
    v[j] = a[j * 256 + threadIdx.x];
    mx = fmaxf(mx, v[j]);
  }
  red[threadIdx.x] = mx;
  __syncthreads();
  for (int st = 128; st; st >>= 1) {
    if (threadIdx.x < st) red[threadIdx.x] = fmaxf(red[threadIdx.x], red[threadIdx.x + st]);
    __syncthreads();
  }
  mx = red[0];
  __syncthreads();
  float sm = 0.f;
  #pragma unroll
  for (int j = 0; j < 16; ++j) {
    v[j] = __expf(v[j] - mx);
    sm += v[j];
  }
  red[threadIdx.x] = sm;
  __syncthreads();
  for (int st = 128; st; st >>= 1) {
    if (threadIdx.x < st) red[threadIdx.x] += red[threadIdx.x + st];
    __syncthreads();
  }
  float inv = 1.0f / red[0];
  #pragma unroll
  for (int j = 0; j < 16; ++j) a[j * 256 + threadIdx.x] = v[j] * inv;
}

__global__ __launch_bounds__(256) void k_context_fb(
    const float* __restrict__ attn, const float* __restrict__ v,
    float* __restrict__ ctx) {
  __shared__ float red[4][DD];
  int row = blockIdx.x;
  int bh = row / UU;
  int b = bh >> 3, h = bh & 7;
  int lane = threadIdx.x & 63;
  int grp = threadIdx.x >> 6;
  const float* a = attn + (long)row * SS;
  float acc = 0.f;
  for (int s = grp; s < SS; s += 4)
    acc += a[s] * v[(((long)b * SS + s) * HH + h) * DD + lane];
  red[grp][lane] = acc;
  __syncthreads();
  if (grp == 0)
    ctx[(long)row * DD + lane] = red[0][lane] + red[1][lane] + red[2][lane] + red[3][lane];
}

extern "C" void kernel_launch(void* const* d_in, const int* in_sizes, int n_in,
                              void* d_out, int out_size, void* d_ws, size_t ws_size,
                              hipStream_t stream) {
  const float* q   = (const float*)d_in[0];
  const float* k   = (const float*)d_in[1];
  const float* v   = (const float*)d_in[2];
  const int*   idx = (const int*)d_in[3];

  float* out  = (float*)d_out;
  float* ctx  = out;                           // B*H*U*D = 46080 floats
  float* attn = out + (long)BB * HH * UU * DD; // B*H*U*S floats

  float* M    = attn;                          // overlay (consumed by topk)
  int*   Mtop = (int*)ctx;                     // overlay (consumed by fused)

  size_t part_bytes  = (size_t)BB * HH * NCH * UU * DD * sizeof(float);   // 5898240
  size_t stats_bytes = (size_t)BB * HH * UU * NCH * sizeof(float);        // 92160
  size_t bkt_bytes   = (1024 + 1024 + 1025) * sizeof(int);                // 12292
  size_t need_new    = part_bytes + stats_bytes + bkt_bytes;

  char* pw = (char*)d_ws;
  float* part  = (float*)pw;
  float* stats = (float*)(pw + part_bytes);
  int*   hist  = (int*)(pw + part_bytes + stats_bytes);
  int*   cursor = hist + 1024;
  int*   off    = hist + 2048;                 // 1025 ints
  unsigned* entries = (unsigned*)pw;           // overlays part (consumed first)

  if (ws_size >= need_new) {
    hipMemsetAsync(hist, 0, 2048 * sizeof(int), stream);   // hist + cursor
    k_hist<<<720, 256, 0, stream>>>(idx, hist);
    k_scan<<<1, 256, 0, stream>>>(hist, off);
    k_scatter<<<720, 256, 0, stream>>>(idx, off, cursor, entries);
    k_gather_M<<<16 * 16, 256, 0, stream>>>(q, k, entries, off, M);
  } else {
    k_compute_M<<<BB * HH * LL / 16, 256, 0, stream>>>(q, k, idx, M);
  }
  k_topk<<<BB * HH, 256, 0, stream>>>(M, Mtop);

  if (ws_size >= part_bytes + stats_bytes) {
    k_fused<<<dim3(NCH, BB * HH), 256, 0, stream>>>(q, k, v, Mtop, attn, part, stats);
    int nctx = (BB * HH * UU * DD) / 256;      // 180
    k_epilogue<<<BB * HH * UU + nctx, 256, 0, stream>>>(stats, part, attn, ctx);
  } else {
    k_scores<<<dim3(SS / 256, BB * HH), 256, 0, stream>>>(q, k, Mtop, attn);
    k_softmax<<<BB * HH * UU, 256, 0, stream>>>(attn);
    k_context_fb<<<BB * HH * UU, 256, 0, stream>>>(attn, v, ctx);
  }
}

// Round 15
// 103.889 us; speedup vs baseline: 3.3559x; 3.3559x over previous
//
#include <hip/hip_runtime.h>

#define BB 2
#define LL 4096
#define SS 4096
#define HH 8
#define DD 64
#define UU 45
#define SCALE 0.125f
#define NCH 32     // softmax/context chunks of 128 s
#define CHK 128

// ---------------------------------------------------------------------------
// K1: M[bh*L + l] = max_u(dot) - sum_u(dot)/S over 45 sampled keys.
// 16-lane slots, per-head float4 gather, width-16 shuffle reduce, bh in low
// 4 bits -> XCD pin (per-XCD K working set 2MB, L2-resident; FETCH ~19MB).
// Measured floor ~48us: 755MB random 256B L2 gather at ~15.7TB/s effective
// (request-rate bound; 5 falsified alternatives: r4 head-fusion, r6 split-u,
// r13 unroll-9, r14 sort-and-stream, wave-doubling).
// ---------------------------------------------------------------------------
__global__ __launch_bounds__(256) void k_compute_M(
    const float* __restrict__ q, const float* __restrict__ k,
    const int* __restrict__ idx, float* __restrict__ M) {
  __shared__ int sidx[16 * UU];
  int tid = threadIdx.x;
  int bh = blockIdx.x & 15;            // low bits -> XCD pin
  int l0 = (blockIdx.x >> 4) << 4;     // 16 l per block
  for (int i = tid; i < 16 * UU; i += 256) sidx[i] = idx[(long)l0 * UU + i];
  __syncthreads();

  int slot = tid >> 4;    // which l within block
  int sub  = tid & 15;    // d-quarter
  int l = l0 + slot;
  int b = bh >> 3, h = bh & 7;

  const float4* qp = (const float4*)(q + (((long)b * LL + l) * HH + h) * DD);
  float4 qq = qp[sub];
  const float* kb = k + (long)b * SS * HH * DD + h * DD;

  float mx = -INFINITY, sm = 0.f;
  #pragma unroll 5
  for (int u = 0; u < UU; ++u) {
    int s = sidx[slot * UU + u];
    float4 kk4 = ((const float4*)(kb + (long)s * (HH * DD)))[sub];
    float p = qq.x * kk4.x + qq.y * kk4.y + qq.z * kk4.z + qq.w * kk4.w;
    #pragma unroll
    for (int off = 8; off; off >>= 1) p += __shfl_xor(p, off, 16);
    mx = fmaxf(mx, p);
    sm += p;
  }
  if (sub == 0) M[(long)bh * LL + l] = mx - sm * (1.0f / SS);
}

// ---------------------------------------------------------------------------
// K2: top-45 per (b,h) via 4-pass radix-select; jax.lax.top_k semantics
// (value desc, ties -> lowest index). One block per bh.
// ---------------------------------------------------------------------------
__global__ __launch_bounds__(256) void k_topk(
    const float* __restrict__ M, int* __restrict__ Mtop) {
  __shared__ unsigned keys[LL];
  __shared__ int hist[256];
  __shared__ int wsum[4];
  __shared__ int sh_bin, sh_gtwin;
  __shared__ int ccount, ecount;
  __shared__ unsigned cand_key[64];
  __shared__ int cand_idx[64];
  __shared__ int elist[LL];

  int bh = blockIdx.x, tid = threadIdx.x;
  int lane = tid & 63, w = tid >> 6;
  const float* m = M + (long)bh * LL;
  for (int i = tid; i < LL; i += 256) {
    union { float f; unsigned u; } cv; cv.f = m[i];
    keys[i] = (cv.u & 0x80000000u) ? ~cv.u : (cv.u | 0x80000000u);
  }
  if (tid == 0) { ccount = 0; ecount = 0; }
  __syncthreads();

  unsigned prefix = 0, pmask = 0;
  int need = UU, above = 0;

  for (int shift = 24; shift >= 0; shift -= 8) {
    hist[tid] = 0;
    __syncthreads();
    #pragma unroll
    for (int j = 0; j < 16; ++j) {
      unsigned kk = keys[tid + (j << 8)];
      if ((kk & pmask) == prefix) atomicAdd(&hist[(kk >> shift) & 255], 1);
    }
    __syncthreads();
    int v = hist[tid];
    int sfx = v;
    #pragma unroll
    for (int st = 1; st < 64; st <<= 1) {
      int o = __shfl_down(sfx, st, 64);
      if (lane + st < 64) sfx += o;
    }
    if (lane == 0) wsum[w] = sfx;
    __syncthreads();
    for (int t = w + 1; t < 4; ++t) sfx += wsum[t];
    int gt = sfx - v;
    if (gt < need && sfx >= need) {
      sh_bin = tid;
      sh_gtwin = gt;
    }
    __syncthreads();
    prefix |= ((unsigned)sh_bin << shift);
    pmask  |= (255u << shift);
    need  -= sh_gtwin;
    above += sh_gtwin;
    __syncthreads();
  }
  unsigned T = prefix;

  #pragma unroll
  for (int j = 0; j < 16; ++j) {
    int i = tid + (j << 8);
    unsigned kk = keys[i];
    if (kk > T)      { int p = atomicAdd(&ccount, 1); cand_key[p] = kk; cand_idx[p] = i; }
    else if (kk == T){ int p = atomicAdd(&ecount, 1); elist[p] = i; }
  }
  __syncthreads();
  int nc = ccount, ne = ecount;
  for (int t = tid; t < nc; t += 256) {
    unsigned kk = cand_key[t]; int ii = cand_idx[t]; int r = 0;
    for (int j = 0; j < nc; ++j)
      r += (cand_key[j] > kk) || (cand_key[j] == kk && cand_idx[j] < ii);
    Mtop[bh * UU + r] = ii;
  }
  for (int t = tid; t < ne; t += 256) {
    int ii = elist[t]; int r = 0;
    for (int j = 0; j < ne; ++j) r += (elist[j] < ii);
    if (r < need) Mtop[bh * UU + above + r] = ii;
  }
}

// ---------------------------------------------------------------------------
// KF: fused scores + exp + chunk-sum + context-partial. grid (NCH, B*H).
// No max subtraction: scores bounded (|s| <= ||Q||||K||/8 ~ 16; e^16 and
// L <= 4096 e^16 are far from fp32 limits), so p~ = exp(score) directly.
// exp(x)/Sum == exp(x-M)/Sum(exp(x-M)) exactly; fp32 diff ~1ulp.
// 3 barriers; P1 FMA chain split 4-way for ILP. (r12 measured optimum;
// r9 u-split, r10 wave-ownership, r13 column-pair all null or regressed.)
// ---------------------------------------------------------------------------
__global__ __launch_bounds__(256) void k_fused(
    const float* __restrict__ q, const float* __restrict__ k,
    const float* __restrict__ v, const int* __restrict__ Mtop,
    float* __restrict__ attn, float* __restrict__ part,
    float* __restrict__ stats) {
  __shared__ float smem[4 * UU * DD];   // 11520 floats (45KB)
  __shared__ float gl[UU];
  float* qr = smem;                     // [0, 2880)
  float* sp = smem + UU * DD;           // [2880, 9536): 128*52

  int ch = blockIdx.x, bh = blockIdx.y;
  int b = bh >> 3, h = bh & 7;
  int tid = threadIdx.x;
  int lane = tid & 63, w = tid >> 6;
  int s0 = ch * CHK;

  for (int i = tid; i < UU * DD; i += 256) {
    int u = i >> 6, d = i & 63;
    int l = Mtop[bh * UU + u];
    qr[i] = q[(((long)b * LL + l) * HH + h) * DD + d];
  }
  __syncthreads();

  // P1: scores -> p~ = exp(score) -> sp. 4 independent FMA chains per u.
  {
    int sl = tid & 127, uh = tid >> 7;
    float4 kr[16];
    const float4* kp = (const float4*)(k + (((long)b * SS + s0 + sl) * HH + h) * DD);
    #pragma unroll
    for (int j = 0; j < 16; ++j) kr[j] = kp[j];
    int u0 = uh ? 23 : 0, u1 = uh ? UU : 23;
    for (int u = u0; u < u1; ++u) {
      const float4* qp = (const float4*)(qr + u * DD);
      float a0 = 0.f, a1 = 0.f, a2 = 0.f, a3 = 0.f;
      #pragma unroll
      for (int j = 0; j < 4; ++j) {
        float4 qA = qp[j];      float4 kA = kr[j];
        float4 qB = qp[j + 4];  float4 kB = kr[j + 4];
        float4 qC = qp[j + 8];  float4 kC = kr[j + 8];
        float4 qD = qp[j + 12]; float4 kD = kr[j + 12];
        a0 += qA.x * kA.x + qA.y * kA.y + qA.z * kA.z + qA.w * kA.w;
        a1 += qB.x * kB.x + qB.y * kB.y + qB.z * kB.z + qB.w * kB.w;
        a2 += qC.x * kC.x + qC.y * kC.y + qC.z * kC.z + qC.w * kC.w;
        a3 += qD.x * kD.x + qD.y * kD.y + qD.z * kD.z + qD.w * kD.w;
      }
      float acc = ((a0 + a1) + (a2 + a3)) * SCALE;
      sp[sl * 52 + u] = __expf(acc);
    }
  }
  __syncthreads();

  // Region 2 (read-only on sp, no internal barrier needed):
  // (a) coalesced unnormalized attn write-out
  for (int i = tid; i < UU * CHK; i += 256) {
    int u = i >> 7, sl = i & 127;
    attn[((long)bh * UU + u) * SS + s0 + sl] = sp[sl * 52 + u];
  }
  // (b) per-u chunk sum
  for (int u = w; u < UU; u += 4) {
    float e = sp[lane * 52 + u] + sp[(lane + 64) * 52 + u];
    #pragma unroll
    for (int off = 32; off; off >>= 1) e += __shfl_xor(e, off, 64);
    if (lane == 0) gl[u] = e;
  }
  // (c) context accumulate (lane = d)
  float acc[UU];
  #pragma unroll
  for (int u = 0; u < UU; ++u) acc[u] = 0.f;
  const float* vb = v + (long)b * SS * HH * DD + h * DD + lane;
  #pragma unroll 2
  for (int j = 0; j < 32; ++j) {
    int sl = (j << 2) + w;
    float vd = vb[(long)(s0 + sl) * (HH * DD)];
    const float* ar = sp + sl * 52;
    #pragma unroll
    for (int g = 0; g < 11; ++g) {
      float4 aa = *(const float4*)(ar + g * 4);
      acc[g * 4 + 0] += aa.x * vd;
      acc[g * 4 + 1] += aa.y * vd;
      acc[g * 4 + 2] += aa.z * vd;
      acc[g * 4 + 3] += aa.w * vd;
    }
    acc[44] += ar[44] * vd;
  }

  __syncthreads();                      // sp reads done; gl complete
  #pragma unroll
  for (int u = 0; u < UU; ++u) smem[(w * UU + u) * DD + lane] = acc[u];
  __syncthreads();
  long base = ((long)bh * NCH + ch) * (UU * DD);
  for (int i = tid; i < UU * DD; i += 256)
    part[base + i] = smem[i] + smem[UU * DD + i] + smem[2 * UU * DD + i] + smem[3 * UU * DD + i];
  if (tid < UU)
    stats[((long)bh * UU + tid) * NCH + ch] = gl[tid];
}

// ---------------------------------------------------------------------------
// KE: epilogue. blocks [0,720): rescale one attn row by 1/L (L = sum of
// chunk sums). blocks [720,900): ctx[e] = sum_ch part / L.
// ---------------------------------------------------------------------------
__global__ __launch_bounds__(256) void k_epilogue(
    const float* __restrict__ stats, const float* __restrict__ part,
    float* __restrict__ attn, float* __restrict__ ctx) {
  __shared__ float sinv;
  int bid = blockIdx.x, tid = threadIdx.x;
  if (bid < BB * HH * UU) {
    long row = bid;                     // bh*UU + u
    const float* st = stats + row * NCH;
    if (tid == 0) {
      float L = 0.f;
      #pragma unroll
      for (int c = 0; c < NCH; ++c) L += st[c];
      sinv = 1.0f / L;
    }
    __syncthreads();
    float inv = sinv;
    float4* a = (float4*)(attn + row * SS);
    #pragma unroll
    for (int g = 0; g < 4; ++g) {
      int i4 = g * 256 + tid;
      float4 vv = a[i4];
      vv.x *= inv; vv.y *= inv; vv.z *= inv; vv.w *= inv;
      a[i4] = vv;
    }
  } else {
    int e = (bid - BB * HH * UU) * 256 + tid;   // < 46080
    int bh = e / (UU * DD);
    int r = e - bh * (UU * DD);
    int u = r >> 6;
    const float* st = stats + ((long)bh * UU + u) * NCH;
    float L = 0.f, s = 0.f;
    #pragma unroll
    for (int c = 0; c < NCH; ++c) {
      L += st[c];
      s += part[((long)bh * NCH + c) * (UU * DD) + r];
    }
    ctx[e] = s / L;
  }
}

// --------------------- fallback path (small ws) ----------------------------
__global__ __launch_bounds__(256) void k_scores(
    const float* __restrict__ q, const float* __restrict__ k,
    const int* __restrict__ Mtop, float* __restrict__ attn) {
  __shared__ float qr[UU * DD];
  int bh = blockIdx.y;
  int b = bh >> 3, h = bh & 7;
  for (int i = threadIdx.x; i < UU * DD; i += 256) {
    int u = i >> 6, d = i & 63;
    int l = Mtop[bh * UU + u];
    qr[i] = q[(((long)b * LL + l) * HH + h) * DD + d];
  }
  __syncthreads();
  int s = blockIdx.x * 256 + threadIdx.x;
  float4 kr[16];
  const float4* kp = (const float4*)(k + (((long)b * SS + s) * HH + h) * DD);
  #pragma unroll
  for (int j = 0; j < 16; ++j) kr[j] = kp[j];
  for (int u = 0; u < UU; ++u) {
    const float4* qp = (const float4*)(qr + u * DD);
    float acc = 0.f;
    #pragma unroll
    for (int j = 0; j < 16; ++j) {
      float4 qq = qp[j];
      acc += qq.x * kr[j].x + qq.y * kr[j].y + qq.z * kr[j].z + qq.w * kr[j].w;
    }
    attn[((long)bh * UU + u) * SS + s] = acc * SCALE;
  }
}

__global__ __launch_bounds__(256) void k_softmax(float* __restrict__ attn) {
  __shared__ float red[256];
  long row = blockIdx.x;
  float* a = attn + row * SS;
  float v[16];
  float mx = -INFINITY;
  #pragma unroll
  for (int j = 0; j < 16; ++j) {
    v[j] = a[j * 256 + threadIdx.x];
    mx = fmaxf(mx, v[j]);
  }
  red[threadIdx.x] = mx;
  __syncthreads();
  for (int st = 128; st; st >>= 1) {
    if (threadIdx.x < st) red[threadIdx.x] = fmaxf(red[threadIdx.x], red[threadIdx.x + st]);
    __syncthreads();
  }
  mx = red[0];
  __syncthreads();
  float sm = 0.f;
  #pragma unroll
  for (int j = 0; j < 16; ++j) {
    v[j] = __expf(v[j] - mx);
    sm += v[j];
  }
  red[threadIdx.x] = sm;
  __syncthreads();
  for (int st = 128; st; st >>= 1) {
    if (threadIdx.x < st) red[threadIdx.x] += red[threadIdx.x + st];
    __syncthreads();
  }
  float inv = 1.0f / red[0];
  #pragma unroll
  for (int j = 0; j < 16; ++j) a[j * 256 + threadIdx.x] = v[j] * inv;
}

__global__ __launch_bounds__(256) void k_context_fb(
    const float* __restrict__ attn, const float* __restrict__ v,
    float* __restrict__ ctx) {
  __shared__ float red[4][DD];
  int row = blockIdx.x;
  int bh = row / UU;
  int b = bh >> 3, h = bh & 7;
  int lane = threadIdx.x & 63;
  int grp = threadIdx.x >> 6;
  const float* a = attn + (long)row * SS;
  float acc = 0.f;
  for (int s = grp; s < SS; s += 4)
    acc += a[s] * v[(((long)b * SS + s) * HH + h) * DD + lane];
  red[grp][lane] = acc;
  __syncthreads();
  if (grp == 0)
    ctx[(long)row * DD + lane] = red[0][lane] + red[1][lane] + red[2][lane] + red[3][lane];
}

extern "C" void kernel_launch(void* const* d_in, const int* in_sizes, int n_in,
                              void* d_out, int out_size, void* d_ws, size_t ws_size,
                              hipStream_t stream) {
  const float* q   = (const float*)d_in[0];
  const float* k   = (const float*)d_in[1];
  const float* v   = (const float*)d_in[2];
  const int*   idx = (const int*)d_in[3];

  float* out  = (float*)d_out;
  float* ctx  = out;                           // B*H*U*D = 46080 floats
  float* attn = out + (long)BB * HH * UU * DD; // B*H*U*S floats

  // Overlays on d_out (stream-ordered write-after-read):
  //  - M at start of attn region (consumed by topk before KF overwrites)
  //  - Mtop at start of ctx region (consumed by KF before KE writes ctx)
  float* M    = attn;
  int*   Mtop = (int*)ctx;

  k_compute_M<<<BB * HH * LL / 16, 256, 0, stream>>>(q, k, idx, M);
  k_topk<<<BB * HH, 256, 0, stream>>>(M, Mtop);

  size_t part_bytes  = (size_t)BB * HH * NCH * UU * DD * sizeof(float);   // 5898240
  size_t stats_bytes = (size_t)BB * HH * UU * NCH * sizeof(float);        // 92160
  if (ws_size >= part_bytes + stats_bytes) {
    float* part  = (float*)d_ws;
    float* stats = (float*)((char*)d_ws + part_bytes);
    k_fused<<<dim3(NCH, BB * HH), 256, 0, stream>>>(q, k, v, Mtop, attn, part, stats);
    int nctx = (BB * HH * UU * DD) / 256;      // 180
    k_epilogue<<<BB * HH * UU + nctx, 256, 0, stream>>>(stats, part, attn, ctx);
  } else {
    k_scores<<<dim3(SS / 256, BB * HH), 256, 0, stream>>>(q, k, Mtop, attn);
    k_softmax<<<BB * HH * UU, 256, 0, stream>>>(attn);
    k_context_fb<<<BB * HH * UU, 256, 0, stream>>>(attn, v, ctx);
  }
}